// Round 3
// baseline (178.790 us; speedup 1.0000x reference)
//
#include <hip/hip_runtime.h>

#define N 1024
#define DD 256
#define EPS 100.0f
#define INV_EPS 0.01f
#define LOG_MU -6.93147180559945f

__device__ __forceinline__ float waveReduceSum(float s) {
#pragma unroll
  for (int m = 1; m <= 32; m <<= 1) s += __shfl_xor(s, m);
  return s;
}

// ---------------- cmat: C[i][j] = sum_k |x[i][k]-y[j][k]|, plus CT ---------
// 64x32 tile per block, grid (32,16)=512 blocks (2/CU), 256 threads.
// Also zeroes duals and the grid-barrier flags for the coop kernel (runs
// strictly before it in stream order -> clean flags every call/replay).
__global__ __launch_bounds__(256) void cmat_kernel(
    const float* __restrict__ x, const float* __restrict__ y,
    float* __restrict__ Cm, float* __restrict__ CT, float* __restrict__ u,
    float* __restrict__ v, int* __restrict__ flags) {
  __shared__ float xs[64][68];
  __shared__ float ys[32][68];
  const int t = threadIdx.x;
  const int bj = blockIdx.x;  // column tile: 32 cols
  const int bi = blockIdx.y;  // row tile: 64 rows
  if (bi == 0 && bj == 0) {   // init duals + barrier flags
    float4 z = make_float4(0.f, 0.f, 0.f, 0.f);
    *reinterpret_cast<float4*>(u + t * 4) = z;
    *reinterpret_cast<float4*>(v + t * 4) = z;
    flags[t] = 0;
    if (t == 0) flags[384] = 0;
  }
  const int tx = t & 15;   // col group: cols tx*2, tx*2+1
  const int ty = t >> 4;   // row group: rows ty*4 .. ty*4+3
  float acc[4][2] = {};
  const float* xg = x + (size_t)(bi * 64) * DD;
  const float* yg = y + (size_t)(bj * 32) * DD;
  const int c0 = tx * 2, c1 = tx * 2 + 1;
  const int yswz = ((c0 >> 3) & 1) << 2;  // same for c0 and c0+1 (c0 even)

  for (int kc = 0; kc < DD; kc += 64) {
    __syncthreads();
#pragma unroll
    for (int it = 0; it < 4; ++it) {  // stage x: 64 rows x 64 k
      const int l = it * 256 + t;
      const int row = l >> 4, kq = l & 15;
      const float4 g =
          *reinterpret_cast<const float4*>(xg + row * DD + kc + kq * 4);
      *reinterpret_cast<float4*>(&xs[row][kq * 4]) = g;
    }
#pragma unroll
    for (int it = 0; it < 2; ++it) {  // stage y: 32 rows x 64 k, bit2-XOR swz
      const int l = it * 256 + t;
      const int row = l >> 4, kq = l & 15;
      const float4 g =
          *reinterpret_cast<const float4*>(yg + row * DD + kc + kq * 4);
      const int col = (kq * 4) ^ (((row >> 3) & 1) << 2);
      *reinterpret_cast<float4*>(&ys[row][col]) = g;
    }
    __syncthreads();
#pragma unroll 2
    for (int kk = 0; kk < 64; kk += 4) {
      float4 xr[4];
#pragma unroll
      for (int r = 0; r < 4; ++r)
        xr[r] = *reinterpret_cast<const float4*>(&xs[ty * 4 + r][kk]);
      const float4 ya = *reinterpret_cast<const float4*>(&ys[c0][kk ^ yswz]);
      const float4 yb = *reinterpret_cast<const float4*>(&ys[c1][kk ^ yswz]);
#pragma unroll
      for (int r = 0; r < 4; ++r) {
        acc[r][0] += fabsf(xr[r].x - ya.x) + fabsf(xr[r].y - ya.y) +
                     fabsf(xr[r].z - ya.z) + fabsf(xr[r].w - ya.w);
        acc[r][1] += fabsf(xr[r].x - yb.x) + fabsf(xr[r].y - yb.y) +
                     fabsf(xr[r].z - yb.z) + fabsf(xr[r].w - yb.w);
      }
    }
  }
  // C write (coalesced float2)
  const int gr0 = bi * 64 + ty * 4;
  const int gc0 = bj * 32 + c0;
#pragma unroll
  for (int r = 0; r < 4; ++r)
    *reinterpret_cast<float2*>(Cm + (size_t)(gr0 + r) * N + gc0) =
        make_float2(acc[r][0], acc[r][1]);
  // CT via LDS transpose (reuse xs), then coalesced float4 stores
  __syncthreads();
#pragma unroll
  for (int r = 0; r < 4; ++r) {
    xs[c0][ty * 4 + r] = acc[r][0];
    xs[c1][ty * 4 + r] = acc[r][1];
  }
  __syncthreads();
#pragma unroll
  for (int it = 0; it < 2; ++it) {
    const int l = it * 256 + t;
    const int crow = l >> 4, cq = l & 15;  // crow: col of C (0..31)
    const float4 val = *reinterpret_cast<const float4*>(&xs[crow][cq * 4]);
    *reinterpret_cast<float4*>(CT + (size_t)(bj * 32 + crow) * N + bi * 64 +
                               cq * 4) = val;
  }
}

// ---------------- persistent Sinkhorn kernel (1 launch, grid barriers) -----
// 256 blocks (1/CU, co-resident) x 256 threads = 1024 waves; wave (b,w) owns
// row i=b*4+w and col j=b*4+w. Barrier: arrive flags[0..255] (one per block,
// no contention) + release word flags[384] = 2*gen + doneBit. All flags are
// zeroed by cmat_kernel each call, gens strictly increase within a launch ->
// no cross-replay staleness.
__device__ __forceinline__ int gsync(int* flags, int gen, int b, int done_in) {
  __shared__ int s_done;
  __syncthreads();
  if (threadIdx.x == 0)
    __hip_atomic_store(flags + b, gen, __ATOMIC_RELEASE,
                       __HIP_MEMORY_SCOPE_AGENT);
  if (b == 0) {
    while (__hip_atomic_load(flags + threadIdx.x, __ATOMIC_ACQUIRE,
                             __HIP_MEMORY_SCOPE_AGENT) < gen)
      __builtin_amdgcn_s_sleep(1);
    __syncthreads();
    if (threadIdx.x == 0)
      __hip_atomic_store(flags + 384, 2 * gen + done_in, __ATOMIC_RELEASE,
                         __HIP_MEMORY_SCOPE_AGENT);
  }
  if (threadIdx.x == 0) {
    int r;
    while ((r = __hip_atomic_load(flags + 384, __ATOMIC_ACQUIRE,
                                  __HIP_MEMORY_SCOPE_AGENT)) < 2 * gen)
      __builtin_amdgcn_s_sleep(1);
    s_done = r - 2 * gen;
  }
  __syncthreads();
  return s_done;
}

__global__ __launch_bounds__(256, 1) void sinkhorn_coop(
    const float* __restrict__ Cm, const float* __restrict__ CT,
    float* __restrict__ u, float* __restrict__ v, float* __restrict__ derr,
    float* __restrict__ partials, int* flags, float* __restrict__ out) {
  const int b = blockIdx.x;
  const int t = threadIdx.x;
  const int lane = t & 63;
  const int w = t >> 6;
  const int i = b * 4 + w;  // my row (and col) index

  float ui = 0.0f, vj = 0.0f;
  int gen = 0;

  for (int it = 0; it < 10; ++it) {
    // ---- row pass: u update (reads all v, own C row) ----
    {
      const float* row = Cm + (size_t)i * N;
      float s = 0.0f;
#pragma unroll
      for (int q = 0; q < 4; ++q) {
        const int j4 = (q * 64 + lane) * 4;
        const float4 c4 = *reinterpret_cast<const float4*>(row + j4);
        const float4 v4 = *reinterpret_cast<const float4*>(v + j4);
        s += expf((ui + v4.x - c4.x) * INV_EPS) +
             expf((ui + v4.y - c4.y) * INV_EPS) +
             expf((ui + v4.z - c4.z) * INV_EPS) +
             expf((ui + v4.w - c4.w) * INV_EPS);
      }
      s = waveReduceSum(s);
      const float un = EPS * (LOG_MU - logf(s + 1e-6f)) + ui;
      if (lane == 0) {
        derr[i] = fabsf(un - ui);
        u[i] = un;
      }
      ui = un;
    }
    gsync(flags, ++gen, b, 0);
    // ---- col pass: v update (reads all u, own CT row) ----
    {
      const float* col = CT + (size_t)i * N;
      float s = 0.0f;
#pragma unroll
      for (int q = 0; q < 4; ++q) {
        const int i4 = (q * 64 + lane) * 4;
        const float4 c4 = *reinterpret_cast<const float4*>(col + i4);
        const float4 u4 = *reinterpret_cast<const float4*>(u + i4);
        s += expf((u4.x + vj - c4.x) * INV_EPS) +
             expf((u4.y + vj - c4.y) * INV_EPS) +
             expf((u4.z + vj - c4.z) * INV_EPS) +
             expf((u4.w + vj - c4.w) * INV_EPS);
      }
      s = waveReduceSum(s);
      const float vn = EPS * (LOG_MU - logf(s + 1e-6f)) + vj;
      if (lane == 0) v[i] = vn;
      vj = vn;
    }
    int newdone = 0;
    if (b == 0 && w == 0) {  // err = sum(derr); done if err < 0.1
      float e = 0.0f;
#pragma unroll
      for (int q = 0; q < 4; ++q) {
        const float4 d4 =
            *reinterpret_cast<const float4*>(derr + (q * 64 + lane) * 4);
        e += d4.x + d4.y + d4.z + d4.w;
      }
      e = waveReduceSum(e);
      newdone = (e < 0.1f) ? 1 : 0;
    }
    if (gsync(flags, ++gen, b, newdone)) break;  // uniform early exit
  }
  // ---- loss: partials[i] = sum_j exp(M_ij) * C_ij ----
  {
    const float* row = Cm + (size_t)i * N;
    float s = 0.0f;
#pragma unroll
    for (int q = 0; q < 4; ++q) {
      const int j4 = (q * 64 + lane) * 4;
      const float4 c4 = *reinterpret_cast<const float4*>(row + j4);
      const float4 v4 = *reinterpret_cast<const float4*>(v + j4);
      s += expf((ui + v4.x - c4.x) * INV_EPS) * c4.x +
           expf((ui + v4.y - c4.y) * INV_EPS) * c4.y +
           expf((ui + v4.z - c4.z) * INV_EPS) * c4.z +
           expf((ui + v4.w - c4.w) * INV_EPS) * c4.w;
    }
    s = waveReduceSum(s);
    if (lane == 0) partials[i] = s;
  }
  gsync(flags, ++gen, b, 0);
  if (b == 0) {  // final reduce of 1024 partials
    __shared__ float red[4];
    const float4 p = *reinterpret_cast<const float4*>(partials + t * 4);
    float s = p.x + p.y + p.z + p.w;
    s = waveReduceSum(s);
    if (lane == 0) red[w] = s;
    __syncthreads();
    if (t == 0) out[0] = red[0] + red[1] + red[2] + red[3];
  }
}

extern "C" void kernel_launch(void* const* d_in, const int* in_sizes, int n_in,
                              void* d_out, int out_size, void* d_ws,
                              size_t ws_size, hipStream_t stream) {
  const float* x = (const float*)d_in[0];  // "output"
  const float* y = (const float*)d_in[1];  // "target"
  float* out = (float*)d_out;

  const size_t nn = (size_t)N * N;
  float* Cm = (float*)d_ws;
  float* CT = Cm + nn;
  float* u = CT + nn;
  float* v = u + N;
  float* derr = v + N;
  float* partials = derr + N;
  int* flags = (int*)(partials + N);  // [0..255] arrive, [384] release

  cmat_kernel<<<dim3(32, 16), 256, 0, stream>>>(x, y, Cm, CT, u, v, flags);
  sinkhorn_coop<<<256, 256, 0, stream>>>(Cm, CT, u, v, derr, partials, flags,
                                         out);
}

// Round 4
// 79.489 us; speedup vs baseline: 2.2492x; 2.2492x over previous
//
#include <hip/hip_runtime.h>

#define N 1024
#define DD 256
#define EPS 100.0f
#define INV_EPS 0.01f
#define LOG_MU -6.93147180559945f

__device__ __forceinline__ float waveReduceSum(float s) {
#pragma unroll
  for (int m = 1; m <= 32; m <<= 1) s += __shfl_xor(s, m);
  return s;
}

// Relaxed agent-scope accesses: cache-bypassing (sc0 sc1), straight to the
// device coherence point. No acquire/release -> no L1/L2 invalidate/writeback.
__device__ __forceinline__ float rloadf(const float* p) {
  return __hip_atomic_load(p, __ATOMIC_RELAXED, __HIP_MEMORY_SCOPE_AGENT);
}
__device__ __forceinline__ void rstoref(float* p, float x) {
  __hip_atomic_store(p, x, __ATOMIC_RELAXED, __HIP_MEMORY_SCOPE_AGENT);
}
__device__ __forceinline__ int rloadi(const int* p) {
  return __hip_atomic_load(p, __ATOMIC_RELAXED, __HIP_MEMORY_SCOPE_AGENT);
}
__device__ __forceinline__ void rstorei(int* p, int x) {
  __hip_atomic_store(p, x, __ATOMIC_RELAXED, __HIP_MEMORY_SCOPE_AGENT);
}

// ---------------- cmat: C[i][j] = sum_k |x[i][k]-y[j][k]|, plus CT ---------
// Also zeroes duals + barrier flags (strictly before coop kernel in stream
// order; its normal stores are flushed at dispatch end -> visible to sc1
// reads of the coop kernel).
__global__ __launch_bounds__(256) void cmat_kernel(
    const float* __restrict__ x, const float* __restrict__ y,
    float* __restrict__ Cm, float* __restrict__ CT, float* __restrict__ u,
    float* __restrict__ v, int* __restrict__ flags) {
  __shared__ float xs[64][68];
  __shared__ float ys[32][68];
  const int t = threadIdx.x;
  const int bj = blockIdx.x;  // column tile: 32 cols
  const int bi = blockIdx.y;  // row tile: 64 rows
  if (bi == 0 && bj == 0) {   // init duals + barrier flags
    float4 z = make_float4(0.f, 0.f, 0.f, 0.f);
    *reinterpret_cast<float4*>(u + t * 4) = z;
    *reinterpret_cast<float4*>(v + t * 4) = z;
    flags[t] = 0;
    flags[256 + t] = 0;
  }
  const int tx = t & 15;   // col group: cols tx*2, tx*2+1
  const int ty = t >> 4;   // row group: rows ty*4 .. ty*4+3
  float acc[4][2] = {};
  const float* xg = x + (size_t)(bi * 64) * DD;
  const float* yg = y + (size_t)(bj * 32) * DD;
  const int c0 = tx * 2, c1 = tx * 2 + 1;
  const int yswz = ((c0 >> 3) & 1) << 2;

  for (int kc = 0; kc < DD; kc += 64) {
    __syncthreads();
#pragma unroll
    for (int it = 0; it < 4; ++it) {  // stage x: 64 rows x 64 k
      const int l = it * 256 + t;
      const int row = l >> 4, kq = l & 15;
      const float4 g =
          *reinterpret_cast<const float4*>(xg + row * DD + kc + kq * 4);
      *reinterpret_cast<float4*>(&xs[row][kq * 4]) = g;
    }
#pragma unroll
    for (int it = 0; it < 2; ++it) {  // stage y: 32 rows x 64 k, bit2-XOR swz
      const int l = it * 256 + t;
      const int row = l >> 4, kq = l & 15;
      const float4 g =
          *reinterpret_cast<const float4*>(yg + row * DD + kc + kq * 4);
      const int col = (kq * 4) ^ (((row >> 3) & 1) << 2);
      *reinterpret_cast<float4*>(&ys[row][col]) = g;
    }
    __syncthreads();
#pragma unroll 2
    for (int kk = 0; kk < 64; kk += 4) {
      float4 xr[4];
#pragma unroll
      for (int r = 0; r < 4; ++r)
        xr[r] = *reinterpret_cast<const float4*>(&xs[ty * 4 + r][kk]);
      const float4 ya = *reinterpret_cast<const float4*>(&ys[c0][kk ^ yswz]);
      const float4 yb = *reinterpret_cast<const float4*>(&ys[c1][kk ^ yswz]);
#pragma unroll
      for (int r = 0; r < 4; ++r) {
        acc[r][0] += fabsf(xr[r].x - ya.x) + fabsf(xr[r].y - ya.y) +
                     fabsf(xr[r].z - ya.z) + fabsf(xr[r].w - ya.w);
        acc[r][1] += fabsf(xr[r].x - yb.x) + fabsf(xr[r].y - yb.y) +
                     fabsf(xr[r].z - yb.z) + fabsf(xr[r].w - yb.w);
      }
    }
  }
  const int gr0 = bi * 64 + ty * 4;
  const int gc0 = bj * 32 + c0;
#pragma unroll
  for (int r = 0; r < 4; ++r)
    *reinterpret_cast<float2*>(Cm + (size_t)(gr0 + r) * N + gc0) =
        make_float2(acc[r][0], acc[r][1]);
  __syncthreads();
#pragma unroll
  for (int r = 0; r < 4; ++r) {
    xs[c0][ty * 4 + r] = acc[r][0];
    xs[c1][ty * 4 + r] = acc[r][1];
  }
  __syncthreads();
#pragma unroll
  for (int it = 0; it < 2; ++it) {
    const int l = it * 256 + t;
    const int crow = l >> 4, cq = l & 15;
    const float4 val = *reinterpret_cast<const float4*>(&xs[crow][cq * 4]);
    *reinterpret_cast<float4*>(CT + (size_t)(bj * 32 + crow) * N + bi * 64 +
                               cq * 4) = val;
  }
}

// Single-stage all-to-all grid barrier, relaxed-only.
// Entry __syncthreads drains vmcnt (all this block's sc1 data stores are at
// the coherence point) before the arrive store; each thread t polls flag t.
__device__ __forceinline__ void gbar(int* flags, int gen) {
  asm volatile("s_waitcnt vmcnt(0)" ::: "memory");
  __syncthreads();
  if (threadIdx.x == 0) rstorei(flags + blockIdx.x, gen);
  while (rloadi(flags + threadIdx.x) < gen) __builtin_amdgcn_s_sleep(2);
  __syncthreads();
}

// 256 blocks (1/CU) x 256 threads; wave (b,w) owns row/col i=b*4+w.
// flags[0..255]=arrive, flags[320]=done word ((gen<<1)|done).
__global__ __launch_bounds__(256, 1) void sinkhorn_coop(
    const float* __restrict__ Cm, const float* __restrict__ CT,
    float* __restrict__ u, float* __restrict__ v, float* __restrict__ derr,
    float* __restrict__ partials, int* flags, float* __restrict__ out) {
  const int b = blockIdx.x;
  const int t = threadIdx.x;
  const int lane = t & 63;
  const int w = t >> 6;
  const int i = b * 4 + w;

  float ui = 0.0f, vj = 0.0f;
  int gen = 0;

  for (int it = 0; it < 10; ++it) {
    // ---- row pass: u update (own C row cached; v via sc1 loads) ----
    {
      const float* row = Cm + (size_t)i * N;
      float s = 0.0f;
#pragma unroll
      for (int q = 0; q < 4; ++q) {
        const int j4 = (q * 64 + lane) * 4;
        const float4 c4 = *reinterpret_cast<const float4*>(row + j4);
        const float v0 = rloadf(v + j4 + 0), v1 = rloadf(v + j4 + 1),
                    v2 = rloadf(v + j4 + 2), v3 = rloadf(v + j4 + 3);
        s += expf((ui + v0 - c4.x) * INV_EPS) +
             expf((ui + v1 - c4.y) * INV_EPS) +
             expf((ui + v2 - c4.z) * INV_EPS) +
             expf((ui + v3 - c4.w) * INV_EPS);
      }
      s = waveReduceSum(s);
      const float un = EPS * (LOG_MU - logf(s + 1e-6f)) + ui;
      if (lane == 0) {
        rstoref(derr + i, fabsf(un - ui));
        rstoref(u + i, un);
      }
      ui = un;
    }
    gbar(flags, ++gen);
    // ---- col pass: v update; b0/w0 also computes done word ----
    {
      const float* col = CT + (size_t)i * N;
      float s = 0.0f;
#pragma unroll
      for (int q = 0; q < 4; ++q) {
        const int i4 = (q * 64 + lane) * 4;
        const float4 c4 = *reinterpret_cast<const float4*>(col + i4);
        const float u0 = rloadf(u + i4 + 0), u1 = rloadf(u + i4 + 1),
                    u2 = rloadf(u + i4 + 2), u3 = rloadf(u + i4 + 3);
        s += expf((u0 + vj - c4.x) * INV_EPS) +
             expf((u1 + vj - c4.y) * INV_EPS) +
             expf((u2 + vj - c4.z) * INV_EPS) +
             expf((u3 + vj - c4.w) * INV_EPS);
      }
      s = waveReduceSum(s);
      const float vn = EPS * (LOG_MU - logf(s + 1e-6f)) + vj;
      if (lane == 0) rstoref(v + i, vn);
      vj = vn;
    }
    ++gen;
    if (b == 0 && w == 0) {  // done word BEFORE arrive flag -> ordered by bar
      float e = 0.0f;
#pragma unroll
      for (int q = 0; q < 4; ++q) {
        const int i4 = (q * 64 + lane) * 4;
        e += rloadf(derr + i4 + 0) + rloadf(derr + i4 + 1) +
             rloadf(derr + i4 + 2) + rloadf(derr + i4 + 3);
      }
      e = waveReduceSum(e);
      if (lane == 0) rstorei(flags + 320, (gen << 1) | (e < 0.1f ? 1 : 0));
    }
    gbar(flags, gen);
    const int dw = rloadi(flags + 320);
    if ((dw >> 1) == gen && (dw & 1)) break;  // uniform early exit
  }
  // ---- loss: partials[i] = sum_j exp(M_ij) * C_ij ----
  {
    const float* row = Cm + (size_t)i * N;
    float s = 0.0f;
#pragma unroll
    for (int q = 0; q < 4; ++q) {
      const int j4 = (q * 64 + lane) * 4;
      const float4 c4 = *reinterpret_cast<const float4*>(row + j4);
      const float v0 = rloadf(v + j4 + 0), v1 = rloadf(v + j4 + 1),
                  v2 = rloadf(v + j4 + 2), v3 = rloadf(v + j4 + 3);
      s += expf((ui + v0 - c4.x) * INV_EPS) * c4.x +
           expf((ui + v1 - c4.y) * INV_EPS) * c4.y +
           expf((ui + v2 - c4.z) * INV_EPS) * c4.z +
           expf((ui + v3 - c4.w) * INV_EPS) * c4.w;
    }
    s = waveReduceSum(s);
    if (lane == 0) rstoref(partials + i, s);
  }
  gbar(flags, ++gen);
  if (b == 0) {  // final reduce of 1024 partials
    __shared__ float red[4];
    float s = rloadf(partials + t * 4 + 0) + rloadf(partials + t * 4 + 1) +
              rloadf(partials + t * 4 + 2) + rloadf(partials + t * 4 + 3);
    s = waveReduceSum(s);
    if (lane == 0) red[w] = s;
    __syncthreads();
    if (t == 0) out[0] = red[0] + red[1] + red[2] + red[3];
  }
}

extern "C" void kernel_launch(void* const* d_in, const int* in_sizes, int n_in,
                              void* d_out, int out_size, void* d_ws,
                              size_t ws_size, hipStream_t stream) {
  const float* x = (const float*)d_in[0];  // "output"
  const float* y = (const float*)d_in[1];  // "target"
  float* out = (float*)d_out;

  const size_t nn = (size_t)N * N;
  float* Cm = (float*)d_ws;
  float* CT = Cm + nn;
  float* u = CT + nn;
  float* v = u + N;
  float* derr = v + N;
  float* partials = derr + N;
  int* flags = (int*)(partials + N);  // [0..255] arrive, [320] done word

  cmat_kernel<<<dim3(32, 16), 256, 0, stream>>>(x, y, Cm, CT, u, v, flags);
  sinkhorn_coop<<<256, 256, 0, stream>>>(Cm, CT, u, v, derr, partials, flags,
                                         out);
}

// Round 5
// 61.787 us; speedup vs baseline: 2.8937x; 1.2865x over previous
//
#include <hip/hip_runtime.h>
#include <stdint.h>

#define N 1024
#define DD 256
#define EPS 100.0f
#define INV_EPS 0.01f
#define LOG_MU -6.93147180559945f

__device__ __forceinline__ float waveReduceSum(float s) {
#pragma unroll
  for (int m = 1; m <= 32; m <<= 1) s += __shfl_xor(s, m);
  return s;
}

// Relaxed agent-scope 64-bit accesses (cache-bypassing, no cache maintenance).
__device__ __forceinline__ uint64_t rload64(const uint64_t* p) {
  return __hip_atomic_load(p, __ATOMIC_RELAXED, __HIP_MEMORY_SCOPE_AGENT);
}
__device__ __forceinline__ void rstore64(uint64_t* p, uint64_t x) {
  __hip_atomic_store(p, x, __ATOMIC_RELAXED, __HIP_MEMORY_SCOPE_AGENT);
}
__device__ __forceinline__ uint64_t packtag(uint32_t tag, float val) {
  return ((uint64_t)tag << 32) | (uint64_t)__float_as_uint(val);
}

// Poll 4 tagged words (thread t owns slots t*4..t*4+3), then write
// exp(val/eps) into sB. All-or-nothing reload keeps the 4 loads pipelined.
__device__ __forceinline__ void stage_exp(const uint64_t* __restrict__ src,
                                          uint32_t want, float* sB, int t) {
  const int base = t * 4;
  for (;;) {
    const uint64_t a0 = rload64(src + base + 0);
    const uint64_t a1 = rload64(src + base + 1);
    const uint64_t a2 = rload64(src + base + 2);
    const uint64_t a3 = rload64(src + base + 3);
    if ((uint32_t)(a0 >> 32) == want && (uint32_t)(a1 >> 32) == want &&
        (uint32_t)(a2 >> 32) == want && (uint32_t)(a3 >> 32) == want) {
      sB[base + 0] = expf(__uint_as_float((uint32_t)a0) * INV_EPS);
      sB[base + 1] = expf(__uint_as_float((uint32_t)a1) * INV_EPS);
      sB[base + 2] = expf(__uint_as_float((uint32_t)a2) * INV_EPS);
      sB[base + 3] = expf(__uint_as_float((uint32_t)a3) * INV_EPS);
      return;
    }
    __builtin_amdgcn_s_sleep(1);
  }
}

#define NTAGS 6160  // U(2048) V(2048) DERR(1024) PART(1024) DONE(16)

// ---- cmat: C=|x-y|_1 tile kernel; writes C, K=exp(-C/eps), KT; zeroes tags.
__global__ __launch_bounds__(256) void cmat_kernel(
    const float* __restrict__ x, const float* __restrict__ y,
    float* __restrict__ Cm, float* __restrict__ Km, float* __restrict__ KTm,
    uint64_t* __restrict__ tags) {
  __shared__ float xs[64][68];
  __shared__ float ys[32][68];
  const int t = threadIdx.x;
  const int bj = blockIdx.x;  // 32-col tile
  const int bi = blockIdx.y;  // 64-row tile
  if (bi == 0 && bj == 0) {   // zero all tag words (coop runs after, in order)
    for (int z = t; z < NTAGS; z += 256) tags[z] = 0;
  }
  const int tx = t & 15;
  const int ty = t >> 4;
  float acc[4][2] = {};
  const float* xg = x + (size_t)(bi * 64) * DD;
  const float* yg = y + (size_t)(bj * 32) * DD;
  const int c0 = tx * 2, c1 = tx * 2 + 1;
  const int yswz = ((c0 >> 3) & 1) << 2;

  for (int kc = 0; kc < DD; kc += 64) {
    __syncthreads();
#pragma unroll
    for (int it = 0; it < 4; ++it) {  // stage x: 64 rows x 64 k
      const int l = it * 256 + t;
      const int row = l >> 4, kq = l & 15;
      const float4 g =
          *reinterpret_cast<const float4*>(xg + row * DD + kc + kq * 4);
      *reinterpret_cast<float4*>(&xs[row][kq * 4]) = g;
    }
#pragma unroll
    for (int it = 0; it < 2; ++it) {  // stage y: 32 rows x 64 k, XOR swizzle
      const int l = it * 256 + t;
      const int row = l >> 4, kq = l & 15;
      const float4 g =
          *reinterpret_cast<const float4*>(yg + row * DD + kc + kq * 4);
      const int col = (kq * 4) ^ (((row >> 3) & 1) << 2);
      *reinterpret_cast<float4*>(&ys[row][col]) = g;
    }
    __syncthreads();
#pragma unroll 2
    for (int kk = 0; kk < 64; kk += 4) {
      float4 xr[4];
#pragma unroll
      for (int r = 0; r < 4; ++r)
        xr[r] = *reinterpret_cast<const float4*>(&xs[ty * 4 + r][kk]);
      const float4 ya = *reinterpret_cast<const float4*>(&ys[c0][kk ^ yswz]);
      const float4 yb = *reinterpret_cast<const float4*>(&ys[c1][kk ^ yswz]);
#pragma unroll
      for (int r = 0; r < 4; ++r) {
        acc[r][0] += fabsf(xr[r].x - ya.x) + fabsf(xr[r].y - ya.y) +
                     fabsf(xr[r].z - ya.z) + fabsf(xr[r].w - ya.w);
        acc[r][1] += fabsf(xr[r].x - yb.x) + fabsf(xr[r].y - yb.y) +
                     fabsf(xr[r].z - yb.z) + fabsf(xr[r].w - yb.w);
      }
    }
  }
  float kv[4][2];
#pragma unroll
  for (int r = 0; r < 4; ++r) {
    kv[r][0] = expf(-acc[r][0] * INV_EPS);
    kv[r][1] = expf(-acc[r][1] * INV_EPS);
  }
  const int gr0 = bi * 64 + ty * 4;
  const int gc0 = bj * 32 + c0;
#pragma unroll
  for (int r = 0; r < 4; ++r) {
    *reinterpret_cast<float2*>(Cm + (size_t)(gr0 + r) * N + gc0) =
        make_float2(acc[r][0], acc[r][1]);
    *reinterpret_cast<float2*>(Km + (size_t)(gr0 + r) * N + gc0) =
        make_float2(kv[r][0], kv[r][1]);
  }
  // KT via LDS transpose of K values
  __syncthreads();
#pragma unroll
  for (int r = 0; r < 4; ++r) {
    xs[c0][ty * 4 + r] = kv[r][0];
    xs[c1][ty * 4 + r] = kv[r][1];
  }
  __syncthreads();
#pragma unroll
  for (int it = 0; it < 2; ++it) {
    const int l = it * 256 + t;
    const int crow = l >> 4, cq = l & 15;
    const float4 val = *reinterpret_cast<const float4*>(&xs[crow][cq * 4]);
    *reinterpret_cast<float4*>(KTm + (size_t)(bj * 32 + crow) * N + bi * 64 +
                               cq * 4) = val;
  }
}

// ---- persistent Sinkhorn: tagged dataflow, no barriers ----
// 256 blocks x 256 threads; wave (b,w) owns row i and col i, i=b*4+w.
// Tag k (1..10) = value after iteration k. U/V double-buffered by k&1
// (overwrite-safe: writer of tag k+2 is transitively ordered after all
// readers of tag k via the done-word gating chain).
__global__ __launch_bounds__(256, 1) void sinkhorn_coop(
    const float* __restrict__ Cm, const float* __restrict__ Km,
    const float* __restrict__ KTm, uint64_t* __restrict__ U,
    uint64_t* __restrict__ V, uint64_t* __restrict__ DERR,
    uint64_t* __restrict__ PART, uint64_t* __restrict__ DONE,
    float* __restrict__ out) {
  __shared__ float sB[N];
  __shared__ float sRed[4];
  __shared__ int sDone;
  const int b = blockIdx.x, t = threadIdx.x;
  const int lane = t & 63, w = t >> 6;
  const int i = b * 4 + w;
  const float* Krow = Km + (size_t)i * N;
  const float* Trow = KTm + (size_t)i * N;
  const float* Crow = Cm + (size_t)i * N;

  float ui = 0.f, vj = 0.f;
  int klast = 0;

  for (int it = 0; it < 10; ++it) {
    const uint32_t k = it + 1;
    // ---- stage b_j = exp(v^{k-1}_j / eps); k-1==0 -> ones ----
    if (it == 0) {
      *reinterpret_cast<float4*>(&sB[t * 4]) = make_float4(1.f, 1.f, 1.f, 1.f);
    } else {
      stage_exp(V + (size_t)((k - 1) & 1) * N, k - 1, sB, t);
    }
    __syncthreads();
    // ---- row pass: S = sum_j K_ij b_j ; u update ----
    {
      float s = 0.f;
#pragma unroll
      for (int q = 0; q < 4; ++q) {
        const int j4 = (q * 64 + lane) * 4;
        const float4 k4 = *reinterpret_cast<const float4*>(Krow + j4);
        s += k4.x * sB[j4] + k4.y * sB[j4 + 1] + k4.z * sB[j4 + 2] +
             k4.w * sB[j4 + 3];
      }
      s = waveReduceSum(s);
      const float a = expf(ui * INV_EPS);
      const float un = EPS * (LOG_MU - logf(a * s + 1e-6f)) + ui;
      const float de = fabsf(un - ui);
      ui = un;
      if (lane == 0) {
        rstore64(U + (size_t)(k & 1) * N + i, packtag(k, ui));
        if (it < 9) rstore64(DERR + i, packtag(k, de));
      }
    }
    __syncthreads();  // all waves done reading sB before restage
    // ---- stage a_j = exp(u^k_j / eps) ----
    stage_exp(U + (size_t)(k & 1) * N, k, sB, t);
    __syncthreads();
    // ---- col pass: S2 = sum_i KT_ji a_i ; v update ----
    {
      float s = 0.f;
#pragma unroll
      for (int q = 0; q < 4; ++q) {
        const int i4 = (q * 64 + lane) * 4;
        const float4 k4 = *reinterpret_cast<const float4*>(Trow + i4);
        s += k4.x * sB[i4] + k4.y * sB[i4 + 1] + k4.z * sB[i4 + 2] +
             k4.w * sB[i4 + 3];
      }
      s = waveReduceSum(s);
      const float vn =
          EPS * (LOG_MU - logf(expf(vj * INV_EPS) * s + 1e-6f)) + vj;
      vj = vn;
      if (lane == 0) rstore64(V + (size_t)(k & 1) * N + i, packtag(k, vj));
    }
    klast = (int)k;
    if (it < 9) {
      // ---- done word: block0/wave0 gathers derr(k) ----
      if (b == 0 && w == 0) {
        float e = 0.f;
#pragma unroll
        for (int q = 0; q < 16; ++q) {
          const int idx = q * 64 + lane;
          uint64_t d;
          while ((uint32_t)((d = rload64(DERR + idx)) >> 32) != k)
            __builtin_amdgcn_s_sleep(1);
          e += __uint_as_float((uint32_t)d);
        }
        e = waveReduceSum(e);
        if (lane == 0)
          rstore64(DONE + it, ((uint64_t)k << 32) | (e < 0.1f ? 1u : 0u));
      }
      if (t == 0) {
        uint64_t d;
        while ((uint32_t)((d = rload64(DONE + it)) >> 32) != k)
          __builtin_amdgcn_s_sleep(1);
        sDone = (int)(d & 1);
      }
      __syncthreads();  // also guards sB restage of next iteration
      if (sDone) break;
    }
  }
  // ---- loss: partial_i = exp(ui/eps) * sum_j b_j K_ij C_ij ----
  __syncthreads();
  stage_exp(V + (size_t)(klast & 1) * N, (uint32_t)klast, sB, t);
  __syncthreads();
  {
    float s = 0.f;
#pragma unroll
    for (int q = 0; q < 4; ++q) {
      const int j4 = (q * 64 + lane) * 4;
      const float4 k4 = *reinterpret_cast<const float4*>(Krow + j4);
      const float4 c4 = *reinterpret_cast<const float4*>(Crow + j4);
      s += (k4.x * c4.x) * sB[j4] + (k4.y * c4.y) * sB[j4 + 1] +
           (k4.z * c4.z) * sB[j4 + 2] + (k4.w * c4.w) * sB[j4 + 3];
    }
    s = waveReduceSum(s);
    if (lane == 0) rstore64(PART + i, packtag(1u, expf(ui * INV_EPS) * s));
  }
  // ---- final reduce: block 0 polls 1024 partials, fixed-order tree ----
  if (b == 0) {
    float acc = 0.f;
#pragma unroll
    for (int q = 0; q < 4; ++q) {
      const int idx = t * 4 + q;
      uint64_t d;
      while ((uint32_t)((d = rload64(PART + idx)) >> 32) != 1u)
        __builtin_amdgcn_s_sleep(1);
      acc += __uint_as_float((uint32_t)d);
    }
    acc = waveReduceSum(acc);
    if (lane == 0) sRed[w] = acc;
    __syncthreads();
    if (t == 0) out[0] = sRed[0] + sRed[1] + sRed[2] + sRed[3];
  }
}

extern "C" void kernel_launch(void* const* d_in, const int* in_sizes, int n_in,
                              void* d_out, int out_size, void* d_ws,
                              size_t ws_size, hipStream_t stream) {
  const float* x = (const float*)d_in[0];  // "output"
  const float* y = (const float*)d_in[1];  // "target"
  float* out = (float*)d_out;

  const size_t nn = (size_t)N * N;
  float* Cm = (float*)d_ws;
  float* Km = Cm + nn;
  float* KTm = Km + nn;
  uint64_t* tags = (uint64_t*)(KTm + nn);
  uint64_t* U = tags;          // 2*N
  uint64_t* V = U + 2 * N;     // 2*N
  uint64_t* DERR = V + 2 * N;  // N
  uint64_t* PART = DERR + N;   // N
  uint64_t* DONE = PART + N;   // 16

  cmat_kernel<<<dim3(32, 16), 256, 0, stream>>>(x, y, Cm, Km, KTm, tags);
  sinkhorn_coop<<<256, 256, 0, stream>>>(Cm, Km, KTm, U, V, DERR, PART, DONE,
                                         out);
}